// Round 1
// baseline (6637.280 us; speedup 1.0000x reference)
//
#include <hip/hip_runtime.h>
#include <hip/hip_bf16.h>
#include <math.h>

// Problem constants (from reference)
#define NSEQ 2048
#define TT   128
#define EE   128
#define HH   256
#define GG   1024   // 4*H
#define LL   1000
#define BB   8      // sequences per block
#define NTHREADS 1024

__device__ __forceinline__ float sigf(float x) { return 1.0f / (1.0f + expf(-x)); }

__global__ void init_out_kernel(float* out) {
    int i = blockIdx.x * blockDim.x + threadIdx.x;
    if (i < HH + 1) out[i] = 0.0f;   // embeds[256] + loss accumulator
}

// One block = 8 sequences, persistent over all timesteps. 1024 threads:
// gate phase: thread tid owns gate row j=tid for all 8 seqs (fp32 float4 dots,
// weights streamed from L2, x/h broadcast-read from LDS). Update phase: gates
// exchanged via LDS, each thread updates 2 (seq, hidden-unit) states.
// Epilogue: fused embeds mean (atomics) + logits + log-softmax loss.
__launch_bounds__(NTHREADS, 1)
__global__ void lstm_fused_kernel(
    const int* __restrict__ tokens, const int* __restrict__ lengths,
    const int* __restrict__ labels, const float* __restrict__ emb,
    const float* __restrict__ Wih,  const float* __restrict__ Whh,
    const float* __restrict__ bih,  const float* __restrict__ bhh,
    const float* __restrict__ Wout, const float* __restrict__ bout,
    float* __restrict__ out)
{
    __shared__ float hs[BB][HH];   // 8 KB
    __shared__ float cs[BB][HH];   // 8 KB
    __shared__ float xs[BB][EE];   // 4 KB
    __shared__ float gl[BB][GG];   // 32 KB: gates during loop, logits in epilogue
    __shared__ int   len[BB];
    __shared__ int   tok[BB];
    __shared__ float redA[16], redB[16];

    const int tid = threadIdx.x;
    const int n0  = blockIdx.x * BB;
    const int j   = tid;           // gate row owned by this thread

    if (tid < BB) len[tid] = lengths[n0 + tid];
    for (int i = tid; i < BB * HH; i += NTHREADS) {
        (&hs[0][0])[i] = 0.0f;
        (&cs[0][0])[i] = 0.0f;
    }
    __syncthreads();

    int maxlen = 0;
#pragma unroll
    for (int b = 0; b < BB; ++b) maxlen = max(maxlen, len[b]);

    const float bsum = bih[j] + bhh[j];

    for (int t = 0; t < maxlen; ++t) {
        // stage tokens, then embedding rows (coalesced: 1024 threads = 8x128)
        if (tid < BB) tok[tid] = tokens[(n0 + tid) * TT + t];
        __syncthreads();
        {
            const int b = tid >> 7, e = tid & 127;
            xs[b][e] = emb[tok[b] * EE + e];
        }
        __syncthreads();

        float acc[BB];
#pragma unroll
        for (int b = 0; b < BB; ++b) acc[b] = bsum;

        // gates[j][b] = b_ih[j]+b_hh[j] + W_ih[j,:]·x[b] + W_hh[j,:]·h[b]
        const float* wi = Wih + j * EE;
        for (int e = 0; e < EE; e += 4) {
            const float4 w = *(const float4*)(wi + e);
#pragma unroll
            for (int b = 0; b < BB; ++b) {
                const float4 x = *(const float4*)(&xs[b][e]);
                acc[b] += w.x * x.x + w.y * x.y + w.z * x.z + w.w * x.w;
            }
        }
        const float* wh = Whh + j * HH;
        for (int e = 0; e < HH; e += 4) {
            const float4 w = *(const float4*)(wh + e);
#pragma unroll
            for (int b = 0; b < BB; ++b) {
                const float4 h = *(const float4*)(&hs[b][e]);
                acc[b] += w.x * h.x + w.y * h.y + w.z * h.z + w.w * h.w;
            }
        }
#pragma unroll
        for (int b = 0; b < BB; ++b) gl[b][j] = acc[b];
        __syncthreads();

        // update phase: gate order i,f,g,o along rows [0,256,512,768]
        {
            const int u  = tid & (HH - 1);
            const int b0 = tid >> 8;   // 0..3, each thread handles b0 and b0+4
#pragma unroll
            for (int q = 0; q < 2; ++q) {
                const int bb = b0 + 4 * q;
                if (t < len[bb]) {
                    const float ig = sigf(gl[bb][u]);
                    const float fg = sigf(gl[bb][u + HH]);
                    const float gg = tanhf(gl[bb][u + 2 * HH]);
                    const float og = sigf(gl[bb][u + 3 * HH]);
                    const float c  = fg * cs[bb][u] + ig * gg;
                    cs[bb][u] = c;
                    hs[bb][u] = og * tanhf(c);
                }
            }
        }
        __syncthreads();
    }

    // ---- epilogue ----
    // embeds = mean(c_f, axis=0): partial sum over this block's 8 seqs
    if (tid < HH) {
        float s = 0.0f;
#pragma unroll
        for (int b = 0; b < BB; ++b) s += cs[b][tid];
        atomicAdd(&out[tid], s * (1.0f / NSEQ));
    }

    // logits[j][b] = b_out[j] + W_out[j,:]·h_f[b]   (j < 1000)
    float lacc[BB];
    if (j < LL) {
        const float bo = bout[j];
#pragma unroll
        for (int b = 0; b < BB; ++b) lacc[b] = bo;
        const float* wo = Wout + j * HH;
        for (int e = 0; e < HH; e += 4) {
            const float4 w = *(const float4*)(wo + e);
#pragma unroll
            for (int b = 0; b < BB; ++b) {
                const float4 h = *(const float4*)(&hs[b][e]);
                lacc[b] += w.x * h.x + w.y * h.y + w.z * h.z + w.w * h.w;
            }
        }
    }
#pragma unroll
    for (int b = 0; b < BB; ++b) gl[b][j] = (j < LL) ? lacc[b] : -INFINITY;
    __syncthreads();

    // per-sequence log-softmax: 128 threads per sequence over 1024 slots
    const int b = tid >> 7, r = tid & 127;
    float m = -INFINITY;
#pragma unroll
    for (int k = 0; k < 8; ++k) m = fmaxf(m, gl[b][r + 128 * k]);
#pragma unroll
    for (int off = 32; off > 0; off >>= 1) m = fmaxf(m, __shfl_xor(m, off, 64));
    const int wav = tid >> 6;
    if ((tid & 63) == 0) redA[wav] = m;
    __syncthreads();
    const float bm = fmaxf(redA[2 * b], redA[2 * b + 1]);

    float s = 0.0f;
#pragma unroll
    for (int k = 0; k < 8; ++k) s += expf(gl[b][r + 128 * k] - bm);
#pragma unroll
    for (int off = 32; off > 0; off >>= 1) s += __shfl_xor(s, off, 64);
    if ((tid & 63) == 0) redB[wav] = s;
    __syncthreads();

    if (r == 0) {
        const float bs  = redB[2 * b] + redB[2 * b + 1];
        const int   lab = labels[n0 + b];
        const float lp  = gl[b][lab] - bm - logf(bs);
        atomicAdd(&out[HH], -lp * (1.0f / NSEQ));
    }
}

extern "C" void kernel_launch(void* const* d_in, const int* in_sizes, int n_in,
                              void* d_out, int out_size, void* d_ws, size_t ws_size,
                              hipStream_t stream)
{
    const int*   tokens  = (const int*)d_in[0];
    const int*   lengths = (const int*)d_in[1];
    const int*   labels  = (const int*)d_in[2];
    const float* emb     = (const float*)d_in[3];
    const float* Wih     = (const float*)d_in[4];
    const float* Whh     = (const float*)d_in[5];
    const float* bih     = (const float*)d_in[6];
    const float* bhh     = (const float*)d_in[7];
    const float* Wout    = (const float*)d_in[8];
    const float* bout    = (const float*)d_in[9];
    float* out = (float*)d_out;

    hipLaunchKernelGGL(init_out_kernel, dim3(2), dim3(256), 0, stream, out);
    hipLaunchKernelGGL(lstm_fused_kernel, dim3(NSEQ / BB), dim3(NTHREADS), 0, stream,
                       tokens, lengths, labels, emb, Wih, Whh, bih, bhh, Wout, bout, out);
}

// Round 2
// 3091.327 us; speedup vs baseline: 2.1471x; 2.1471x over previous
//
#include <hip/hip_runtime.h>
#include <hip/hip_bf16.h>
#include <math.h>

// Problem constants
#define NSEQ 2048
#define TT   128
#define EE   128
#define HH   256
#define GG   1024      // 4*H gate rows
#define LL   1000
#define BS   16        // sequences per block
#define NT   512       // threads per block (8 waves)
#define NBLK (NSEQ / BS)   // 128 blocks
#define NKT  12        // K tiles of 32: 4 (x: E=128) + 8 (h: H=256)
#define NMT  64        // M tiles of 16: 1024 gate rows
#define NKT_O 8        // K tiles for output GEMM (H=256)
#define WSA_ELEMS (NMT * NKT * 64 * 8)      // 393216 bf16 = 768 KB
#define WSO_ELEMS (NMT * NKT_O * 64 * 8)    // 262144 bf16 = 512 KB

typedef __attribute__((ext_vector_type(8))) short bf16x8;
typedef __attribute__((ext_vector_type(4))) float f32x4;

__device__ __forceinline__ unsigned short f2bf(float f) {
    union { float f; unsigned u; } v; v.f = f;
    unsigned r = v.u + 0x7FFF + ((v.u >> 16) & 1);   // round-to-nearest-even
    return (unsigned short)(r >> 16);
}
__device__ __forceinline__ float sigf(float x) { return 1.0f / (1.0f + __expf(-x)); }
__device__ __forceinline__ float tanh_fast(float x) { return 1.0f - 2.0f / (1.0f + __expf(2.0f * x)); }

__global__ void init_out_kernel(float* out) {
    int i = blockIdx.x * blockDim.x + threadIdx.x;
    if (i < HH + 1) out[i] = 0.0f;
}

// Pre-shuffle weights into MFMA A-fragment order, bf16.
// wsA: A[row][k] for gates; row-major tiles: ((mt*12+kt)*64+lane)*8+j
//      element = A[mt*16 + (lane&15)][kt*32 + (lane>>4)*8 + j], k<128 -> W_ih, else W_hh
// wsO: same for W_out (rows >= 1000 zero-padded), 8 k-tiles over H=256.
__global__ void convert_weights(const float* __restrict__ Wih, const float* __restrict__ Whh,
                                const float* __restrict__ Wout,
                                unsigned short* __restrict__ wsA, unsigned short* __restrict__ wsO) {
    int gid = blockIdx.x * blockDim.x + threadIdx.x;
    if (gid < NMT * NKT * 64) {
        int lane = gid & 63, tile = gid >> 6;
        int kt = tile % NKT, mt = tile / NKT;
        int row = mt * 16 + (lane & 15);
        int kb  = kt * 32 + (lane >> 4) * 8;
        unsigned short o[8];
#pragma unroll
        for (int j = 0; j < 8; ++j) {
            int k = kb + j;
            float v = (k < EE) ? Wih[row * EE + k] : Whh[row * HH + (k - EE)];
            o[j] = f2bf(v);
        }
        uint4 pk;
        pk.x = o[0] | ((unsigned)o[1] << 16); pk.y = o[2] | ((unsigned)o[3] << 16);
        pk.z = o[4] | ((unsigned)o[5] << 16); pk.w = o[6] | ((unsigned)o[7] << 16);
        *(uint4*)(wsA + (size_t)gid * 8) = pk;
    } else {
        int g2 = gid - NMT * NKT * 64;
        if (g2 < NMT * NKT_O * 64) {
            int lane = g2 & 63, tile = g2 >> 6;
            int kt = tile % NKT_O, mt = tile / NKT_O;
            int row = mt * 16 + (lane & 15);
            int ub  = kt * 32 + (lane >> 4) * 8;
            unsigned short o[8];
#pragma unroll
            for (int j = 0; j < 8; ++j)
                o[j] = (row < LL) ? f2bf(Wout[row * HH + ub + j]) : (unsigned short)0;
            uint4 pk;
            pk.x = o[0] | ((unsigned)o[1] << 16); pk.y = o[2] | ((unsigned)o[3] << 16);
            pk.z = o[4] | ((unsigned)o[5] << 16); pk.w = o[6] | ((unsigned)o[7] << 16);
            *(uint4*)(wsO + (size_t)g2 * 8) = pk;
        }
    }
}

// Fused LSTM: 1 block = 16 seqs, 8 waves. Per step: gates = Wsh @ xh via MFMA
// (B-fragments in double-buffered LDS), in-register cell update, h re-written
// as next step's B-fragments. Epilogue: embeds mean + logits GEMM + log-softmax.
__launch_bounds__(NT, 2)
__global__ void lstm_mfma_kernel(
    const int* __restrict__ tokens, const int* __restrict__ lengths,
    const int* __restrict__ labels, const float* __restrict__ emb,
    const float* __restrict__ bih,  const float* __restrict__ bhh,
    const float* __restrict__ bout,
    const unsigned short* __restrict__ wsA, const unsigned short* __restrict__ wsO,
    float* __restrict__ out)
{
    __shared__ unsigned short fr[2][NKT * 64 * 8];   // 2 x 12 KB B-fragment buffers
    __shared__ float redm[8][16];
    __shared__ float reds[8][16];
    __shared__ float labLogit[16];
    __shared__ int   labv[16];

    const int tid = threadIdx.x;
    const int w  = tid >> 6;        // wave 0..7
    const int l  = tid & 63;        // lane
    const int lq = l >> 4;          // row-group 0..3
    const int ls = l & 15;          // seq (col) 0..15
    const int n0 = blockIdx.x * BS;

    // per-lane length + block maxlen via shuffle (each 16-lane group holds all 16 seqs)
    const int len_s = lengths[n0 + ls];
    int maxlen = len_s;
#pragma unroll
    for (int m = 1; m < 16; m <<= 1) maxlen = max(maxlen, __shfl_xor(maxlen, m, 64));

    if (tid < 16) labv[tid] = labels[n0 + tid];

    // per-thread gate biases: acc init value. row = mt*16 + 4*lq + r, mt = g*16+2w+jj
    f32x4 biasv[4][2];
#pragma unroll
    for (int g = 0; g < 4; ++g)
#pragma unroll
        for (int jj = 0; jj < 2; ++jj)
#pragma unroll
            for (int r = 0; r < 4; ++r) {
                int row = (g * 16 + 2 * w + jj) * 16 + 4 * lq + r;
                biasv[g][jj][r] = bih[row] + bhh[row];
            }

    float c_reg[2][4], h_reg[2][4];
#pragma unroll
    for (int jj = 0; jj < 2; ++jj)
#pragma unroll
        for (int r = 0; r < 4; ++r) { c_reg[jj][r] = 0.0f; h_reg[jj][r] = 0.0f; }

    // ---- helpers (macros via lambdas) ----
    // write this thread's 8 h values (bf16) into fragment buffer `buf`
    auto writeH = [&](int buf) {
#pragma unroll
        for (int jj = 0; jj < 2; ++jj) {
            uint2 pk;
            pk.x = f2bf(h_reg[jj][0]) | ((unsigned)f2bf(h_reg[jj][1]) << 16);
            pk.y = f2bf(h_reg[jj][2]) | ((unsigned)f2bf(h_reg[jj][3]) << 16);
            // kt = 4+w ; lane' = ls + 16*(2*jj + (l>>5)) ; short-offset 4*(lq&1)
            unsigned short* p = &fr[buf][(((4 + w) * 64) + ls + 16 * (2 * jj + (l >> 5))) * 8 + 4 * (lq & 1)];
            *(uint2*)p = pk;
        }
    };

    const int sseq = tid & 15;          // staging map: seq
    const int sk0  = (tid >> 4) * 4;    // staging map: k base (0..124)

    auto stageWrite = [&](int buf, float4 xv) {
        uint2 pk;
        pk.x = f2bf(xv.x) | ((unsigned)f2bf(xv.y) << 16);
        pk.y = f2bf(xv.z) | ((unsigned)f2bf(xv.w) << 16);
        unsigned short* p = &fr[buf][(((sk0 >> 5) * 64) + sseq + 16 * ((sk0 >> 3) & 3)) * 8 + (sk0 & 4)];
        *(uint2*)p = pk;
    };

    // ---- prologue: h=0 frags + x[0] into buf 0 ----
    writeH(0);
    {
        int tok = tokens[(n0 + sseq) * TT + 0];
        float4 xv = *(const float4*)(emb + (size_t)tok * EE + sk0);
        stageWrite(0, xv);
    }
    __syncthreads();

    // ---- recurrence ----
    for (int t = 0; t < maxlen; ++t) {
        const int cur = t & 1, nxt = cur ^ 1;
        const bool doStage = (t + 1 < maxlen);

        // B fragments for this step (LDS, conflict-free contiguous)
        bf16x8 bq[NKT];
#pragma unroll
        for (int kt = 0; kt < NKT; ++kt)
            bq[kt] = *(const bf16x8*)&fr[cur][(kt * 64 + l) * 8];

        // issue next-step embedding gather early (latency hidden behind GEMM)
        float4 xv;
        if (doStage) {
            int tok = tokens[(n0 + sseq) * TT + t + 1];
            xv = *(const float4*)(emb + (size_t)tok * EE + sk0);
        }

        // gate GEMM: wave w owns mt = g*16 + 2w + jj  (units [32w, 32w+32))
        f32x4 acc[4][2];
#pragma unroll
        for (int g = 0; g < 4; ++g)
#pragma unroll
            for (int jj = 0; jj < 2; ++jj) {
                const int mt = g * 16 + 2 * w + jj;
                const bf16x8* ap = (const bf16x8*)wsA + (size_t)mt * NKT * 64 + l;
                bf16x8 af[NKT];
#pragma unroll
                for (int kt = 0; kt < NKT; ++kt) af[kt] = ap[kt * 64];
                f32x4 a = biasv[g][jj];
#pragma unroll
                for (int kt = 0; kt < NKT; ++kt)
                    a = __builtin_amdgcn_mfma_f32_16x16x32_bf16(af[kt], bq[kt], a, 0, 0, 0);
                acc[g][jj] = a;
            }

        // in-register LSTM cell update (C-layout: row = 4*lq + r within tile, col = ls)
        const bool live = (t < len_s);
#pragma unroll
        for (int jj = 0; jj < 2; ++jj)
#pragma unroll
            for (int r = 0; r < 4; ++r) {
                if (live) {
                    float ig = sigf(acc[0][jj][r]);
                    float fg = sigf(acc[1][jj][r]);
                    float gg = tanh_fast(acc[2][jj][r]);
                    float og = sigf(acc[3][jj][r]);
                    float c  = fg * c_reg[jj][r] + ig * gg;
                    c_reg[jj][r] = c;
                    h_reg[jj][r] = og * tanh_fast(c);
                }
            }

        writeH(nxt);
        if (doStage) stageWrite(nxt, xv);
        __syncthreads();
    }

    // ---- epilogue 1: embeds = mean(c_f) ----
#pragma unroll
    for (int jj = 0; jj < 2; ++jj)
#pragma unroll
        for (int r = 0; r < 4; ++r) {
            float v = c_reg[jj][r];
            v += __shfl_xor(v, 1, 64);
            v += __shfl_xor(v, 2, 64);
            v += __shfl_xor(v, 4, 64);
            v += __shfl_xor(v, 8, 64);
            if (ls == 0) {
                int u = 32 * w + 16 * jj + 4 * lq + r;
                atomicAdd(&out[u], v * (1.0f / NSEQ));
            }
        }

    // ---- epilogue 2: logits GEMM from final h fragments + log-softmax ----
    const int fin = maxlen & 1;
    bf16x8 bq2[NKT_O];
#pragma unroll
    for (int kt = 0; kt < NKT_O; ++kt)
        bq2[kt] = *(const bf16x8*)&fr[fin][((4 + kt) * 64 + l) * 8];

    float vals[8][4];
    float lmax = -INFINITY;
#pragma unroll
    for (int i = 0; i < 8; ++i) {
        const int mt = 8 * w + i;
        const bf16x8* ap = (const bf16x8*)wsO + (size_t)mt * NKT_O * 64 + l;
        bf16x8 af[NKT_O];
#pragma unroll
        for (int kt = 0; kt < NKT_O; ++kt) af[kt] = ap[kt * 64];
        f32x4 a = {0.0f, 0.0f, 0.0f, 0.0f};
#pragma unroll
        for (int kt = 0; kt < NKT_O; ++kt)
            a = __builtin_amdgcn_mfma_f32_16x16x32_bf16(af[kt], bq2[kt], a, 0, 0, 0);
#pragma unroll
        for (int r = 0; r < 4; ++r) {
            int cls = mt * 16 + 4 * lq + r;
            float v = (cls < LL) ? (a[r] + bout[cls]) : -INFINITY;
            vals[i][r] = v;
            lmax = fmaxf(lmax, v);
            if (cls == labv[ls]) labLogit[ls] = v;   // unique writer per slot
        }
    }
    lmax = fmaxf(lmax, __shfl_xor(lmax, 16, 64));
    lmax = fmaxf(lmax, __shfl_xor(lmax, 32, 64));
    if (l < 16) redm[w][l] = lmax;
    __syncthreads();

    float bm = redm[0][ls];
#pragma unroll
    for (int w2 = 1; w2 < 8; ++w2) bm = fmaxf(bm, redm[w2][ls]);

    float lsum = 0.0f;
#pragma unroll
    for (int i = 0; i < 8; ++i)
#pragma unroll
        for (int r = 0; r < 4; ++r) lsum += __expf(vals[i][r] - bm);
    lsum += __shfl_xor(lsum, 16, 64);
    lsum += __shfl_xor(lsum, 32, 64);
    if (l < 16) reds[w][l] = lsum;
    __syncthreads();

    if (tid < 16) {
        float tot = 0.0f;
#pragma unroll
        for (int w2 = 0; w2 < 8; ++w2) tot += reds[w2][tid];
        float lp = labLogit[tid] - bm - __logf(tot);
        atomicAdd(&out[HH], -lp * (1.0f / NSEQ));
    }
}

extern "C" void kernel_launch(void* const* d_in, const int* in_sizes, int n_in,
                              void* d_out, int out_size, void* d_ws, size_t ws_size,
                              hipStream_t stream)
{
    const int*   tokens  = (const int*)d_in[0];
    const int*   lengths = (const int*)d_in[1];
    const int*   labels  = (const int*)d_in[2];
    const float* emb     = (const float*)d_in[3];
    const float* Wih     = (const float*)d_in[4];
    const float* Whh     = (const float*)d_in[5];
    const float* bih     = (const float*)d_in[6];
    const float* bhh     = (const float*)d_in[7];
    const float* Wout    = (const float*)d_in[8];
    const float* bout    = (const float*)d_in[9];
    float* out = (float*)d_out;

    unsigned short* wsA = (unsigned short*)d_ws;
    unsigned short* wsO = wsA + WSA_ELEMS;

    hipLaunchKernelGGL(init_out_kernel, dim3(2), dim3(256), 0, stream, out);
    {
        int nthr = NMT * NKT * 64 + NMT * NKT_O * 64;   // 81920
        hipLaunchKernelGGL(convert_weights, dim3((nthr + 255) / 256), dim3(256), 0, stream,
                           Wih, Whh, Wout, wsA, wsO);
    }
    hipLaunchKernelGGL(lstm_mfma_kernel, dim3(NBLK), dim3(NT), 0, stream,
                       tokens, lengths, labels, emb, bih, bhh, bout, wsA, wsO, out);
}